// Round 16
// baseline (28665.601 us; speedup 1.0000x reference)
//
#include <hip/hip_runtime.h>
#include <hip/hip_bf16.h>
#include <hip/hip_fp16.h>

typedef unsigned int u32;
typedef unsigned long long u64;
typedef __fp16 h2t __attribute__((ext_vector_type(2)));

// ---------------- dims ----------------
#define T_STEPS_D 128
#define NBATCH 512

// ws layout (u32 element offsets). Weights f16, QUAD-packed:
// quad q (= k-pairs 2q,2q+1), column n: u32[q*2N + 2n + s], s = pair slot (0/1).
#define OFF_TWI   0L         // pairs 278 (150 t_Wi + 128 t_Wh), N=1024
#define OFF_AWI   284672L    // pairs 70 (38 a_Wi [2 zero-pad rows] + 32 a_Wh), N=256
#define OFF_VWI   302592L    // pairs 50 (18 v_Wi + 32 v_Wh), N=256
#define OFF_A1W1  315392L    // pairs 384, N=512
#define OFF_A1W2  512000L    // pairs 256, N=768
#define OFF_A2W1  708608L    // pairs 384, N=512 (K-half0 done by role A, half1 by B)
#define OFF_A2W2  905216L    // pairs 256, N=256
#define OFF_GW1   970752L    // pairs 512, N=1024
#define OFF_GW2   1495040L   // pairs 256, N=512
#define OFF_OW1   1626112L   // pairs 320, N=512
#define U32_TOTAL 1789952L   // fp32 packed biases follow (1536 floats)
// pipeline comm regions (u32 offsets)
#define FLAGS_OFF 1791744L   // flagA[128], flagB[128] (memset each launch)
#define ATTQ_OFF  1792000L   // u32: 4 bufs x 512 rows x 384 pairs (8B aligned)
#define OWP_OFF   2578432L   // f32 bits: 512 rows x 512
#define APQ_OFF   2840576L   // u64-packed f32 pairs: 4 bufs x 512 rows x 256 (a2w1 half0 partials)
#define ATOMIC_RLX_AG(p, v) __hip_atomic_store((p), (v), __ATOMIC_RELAXED, __HIP_MEMORY_SCOPE_AGENT)
#define ATOMIC_LD_AG(p)     __hip_atomic_load((p), __ATOMIC_RELAXED, __HIP_MEMORY_SCOPE_AGENT)

__device__ __forceinline__ float sigm(float x) { return 1.f / (1.f + __expf(-x)); }
__device__ __forceinline__ float tanh_fast(float x) {
    float e = __expf(2.f * x);
    return 1.f - 2.f / (e + 1.f);
}
__device__ __forceinline__ float dot2(u32 a, u32 b, float c) {
    union { u32 u; h2t h; } x, y; x.u = a; y.u = b;
#if __has_builtin(__builtin_amdgcn_fdot2)
    return __builtin_amdgcn_fdot2(x.h, y.h, c, false);
#else
    c += (float)x.h[0] * (float)y.h[0];
    c += (float)x.h[1] * (float)y.h[1];
    return c;
#endif
}
__device__ __forceinline__ u32 pk2(float a, float b) {
    union { h2t h; u32 u; } z;
    z.h = __builtin_amdgcn_cvt_pkrtz(a, b);
    return z.u;
}

// ---- weight block loads: one block = 8 k-pairs = 4 quads ----
__device__ __forceinline__ void gp_load1(u32* buf, const u32* __restrict__ wp, int N) {
#pragma unroll
    for (int q = 0; q < 4; ++q) {
        uint2 v = *(const uint2*)(wp + q * 2 * N);
        buf[2 * q] = v.x; buf[2 * q + 1] = v.y;
    }
}
__device__ __forceinline__ void gp_load2(u32* buf, const u32* __restrict__ wp, int N) {
#pragma unroll
    for (int q = 0; q < 4; ++q) {
        uint4 v = *(const uint4*)(wp + q * 2 * N);
        buf[4 * q] = v.x; buf[4 * q + 1] = v.y; buf[4 * q + 2] = v.z; buf[4 * q + 3] = v.w;
    }
}

// compute one block: 8 k-pairs x 4 rows x NC cols. acc[NC*r+c].
template<int NC>
__device__ __forceinline__ void gp_comp(float* acc, const u32* __restrict__ a, int stA,
                                        int kb, const u32* buf) {
#pragma unroll
    for (int r = 0; r < 4; ++r) {
        uint4 xa = *(const uint4*)(a + r * stA + kb);
        uint4 xb = *(const uint4*)(a + r * stA + kb + 4);
        u32 av[8] = {xa.x, xa.y, xa.z, xa.w, xb.x, xb.y, xb.z, xb.w};
#pragma unroll
        for (int p = 0; p < 8; ++p) {
            if constexpr (NC == 1) {
                acc[r] = dot2(buf[p], av[p], acc[r]);
            } else {
                acc[2 * r]     = dot2(buf[4 * (p >> 1) + (p & 1)],     av[p], acc[2 * r]);
                acc[2 * r + 1] = dot2(buf[4 * (p >> 1) + 2 + (p & 1)], av[p], acc[2 * r + 1]);
            }
        }
    }
}

// acc[NC*r+c] += sum_k a[r][k] * W[k][col_base+c]. Register prefetch pipeline.
template<int NC, int DEPTH>
__device__ __forceinline__ void gpart(float* acc, const u32* __restrict__ a, int k2, int stA,
                                      const u32* __restrict__ w, int N)
{
    const int nb = k2 >> 3;
    u32 b0[NC * 8], b1[NC * 8], b2[NC * 8];
#define GLOAD(B, P) do { if constexpr (NC == 1) gp_load1(B, w + (long)(P) * 8 * N, N); \
                         else gp_load2(B, w + (long)(P) * 8 * N, N); } while (0)
    if (nb > 0) GLOAD(b0, 0);
    if (DEPTH > 1 && nb > 1) GLOAD(b1, 1);
    if (DEPTH > 2 && nb > 2) GLOAD(b2, 2);
    int i = 0;
    while (i < nb) {
        gp_comp<NC>(acc, a, stA, i * 8, b0);
        if (i + DEPTH < nb) GLOAD(b0, i + DEPTH);
        ++i; if (i >= nb) break;
        gp_comp<NC>(acc, a, stA, i * 8, b1);
        if (i + DEPTH < nb) GLOAD(b1, i + DEPTH);
        ++i; if (i >= nb) break;
        if (DEPTH > 2) {
            gp_comp<NC>(acc, a, stA, i * 8, b2);
            if (i + DEPTH < nb) GLOAD(b2, i + DEPTH);
            ++i;
        }
    }
#undef GLOAD
    for (int p = nb * 8; p < k2; ++p) {     // tail (<8 pairs)
        const u32* wp = w + (long)(p >> 1) * 2 * N + (p & 1);
#pragma unroll
        for (int r = 0; r < 4; ++r) {
            u32 aa = a[r * stA + p];
            if constexpr (NC == 1) {
                acc[r] = dot2(wp[0], aa, acc[r]);
            } else {
                acc[2 * r]     = dot2(wp[0], aa, acc[2 * r]);
                acc[2 * r + 1] = dot2(wp[2], aa, acc[2 * r + 1]);
            }
        }
    }
}

// -------- prologue kernels --------
__global__ void k_transpose(const float* __restrict__ src, unsigned short* __restrict__ dst,
                            int N, int K, int strideU, int rowOffK, int colOff)
{
    long i = (long)blockIdx.x * 256 + threadIdx.x;
    if (i >= (long)N * K) return;
    int n = (int)(i / K);
    int k = (int)(i - (long)n * K);
    __half h = __float2half(src[i]);
    long kk = k + rowOffK;
    long idx32 = (kk >> 2) * 2L * strideU + 2L * (colOff + n) + ((kk >> 1) & 1);
    dst[idx32 * 2 + (kk & 1)] = __half_as_ushort(h);
}

__global__ void k_packbias(const float* __restrict__ g1b1, const float* __restrict__ g2b1,
                           const float* __restrict__ g1b2, const float* __restrict__ g2b2,
                           float* __restrict__ gb)
{
    int i = blockIdx.x * 256 + threadIdx.x;
    if (i < 512) gb[i] = g1b1[i];
    else if (i < 1024) gb[i] = g2b1[i - 512];
    else if (i < 1280) gb[i] = g1b2[i - 1024];
    else if (i < 1536) gb[i] = g2b2[i - 1280];
}

// -------- main: 256 WGs x 512 threads; role split by XCD (bid%8) --------
// A (XCD 0-3): LSTMs + attn1 + softmax + attended + a2w1-half0  (~3.24 MB/step)
// B (XCD 4-7): a2w1-half1 + a2w2 + gates + memory               (~3.28 MB/step)
// Cross-XCD payloads via AGENT-scope atomics. flagB released only after B copies
// BOTH attq and apq into LDS; flagA released after A writes both.
__global__ __launch_bounds__(512, 2)
void fused_rnn(const float* __restrict__ x_p,
               const float* __restrict__ c_t0, const float* __restrict__ c_a0,
               const float* __restrict__ c_v0, const float* __restrict__ mem0,
               const float* __restrict__ t_b, const float* __restrict__ a_b,
               const float* __restrict__ v_b,
               const float* __restrict__ a1b1, const float* __restrict__ a1b2,
               const float* __restrict__ a2b1, const float* __restrict__ a2b2,
               const float* __restrict__ ob1, const float* __restrict__ ow2,
               const float* __restrict__ ob2,
               const u32* __restrict__ wsu, const float* __restrict__ wsf,
               u32* wsrw,
               float* __restrict__ out)
{
    const int tid = threadIdx.x;
    const int xcd = (int)blockIdx.x & 7;
    const bool isA = xcd < 4;
    const int g = ((int)blockIdx.x >> 3) * 4 + (xcd & 3);
    const int row0 = g * 4;

    int* flagA = (int*)(wsrw + FLAGS_OFF);
    int* flagB = flagA + 128;
    u32* attq = wsrw + ATTQ_OFF;
    u32* owp = wsrw + OWP_OFF;
    u64* apq = (u64*)(wsrw + APQ_OFF);

    // fp32 buffers
    __shared__ alignas(16) float sZ[4][1024];
    __shared__ alignas(16) float sZa[4][256];
    __shared__ alignas(16) float sZv[4][256];
    __shared__ alignas(16) float sTc[4][256];
    __shared__ alignas(16) float sAc[4][64];
    __shared__ alignas(16) float sVc[4][64];
    __shared__ alignas(16) float sM[4][256];
    __shared__ alignas(16) float sCs[4][768];
    __shared__ alignas(16) float sCp[2][4][256];
    __shared__ alignas(16) float sHid[4][512];
    __shared__ alignas(16) float sPart[2][4][512];
    // packed f16-pair buffers
    __shared__ alignas(16) u32 pX[4][212];
    __shared__ alignas(16) u32 pCs[4][384];
    __shared__ alignas(16) u32 pTh[4][128];
    __shared__ alignas(16) u32 pAh[4][32];
    __shared__ alignas(16) u32 pVh[4][32];
    __shared__ alignas(16) u32 pM[4][128];
    __shared__ alignas(16) u32 pHid[4][256];
    __shared__ alignas(16) u32 pZ[4][512];
    __shared__ float sRed[4];
    __shared__ float sRed2[8][4];

    if (isA) {
        // ================= ROLE A =================
        for (int i = tid; i < 4 * 128; i += 512) {
            int r = i >> 7, j2 = i & 127, j = 2 * j2;
            sTc[r][j] = c_t0[(row0 + r) * 256 + j];
            sTc[r][j + 1] = c_t0[(row0 + r) * 256 + j + 1];
            pTh[r][j2] = 0u;
        }
        for (int i = tid; i < 4 * 32; i += 512) {
            int r = i >> 5, j2 = i & 31, j = 2 * j2;
            sAc[r][j] = c_a0[(row0 + r) * 64 + j]; sAc[r][j + 1] = c_a0[(row0 + r) * 64 + j + 1];
            sVc[r][j] = c_v0[(row0 + r) * 64 + j]; sVc[r][j + 1] = c_v0[(row0 + r) * 64 + j + 1];
            pAh[r][j2] = 0u; pVh[r][j2] = 0u;
        }
        if (tid < 12) pX[tid / 3][189 + tid % 3] = 0u;
        __syncthreads();

        for (int t = 0; t < T_STEPS_D; ++t) {
            if (t >= 4) {   // quad-buffer reuse guard (attq + apq)
                if (tid == 0) {
                    while (__hip_atomic_load(flagB + g, __ATOMIC_ACQUIRE,
                                             __HIP_MEMORY_SCOPE_AGENT) < t - 3)
                        __builtin_amdgcn_s_sleep(2);
                }
                __syncthreads();
            }
            // ---- stage 1 ----
            const float* xb = x_p + ((long)t * NBATCH + row0) * 410;
            for (int i = tid; i < 4 * 205; i += 512) {
                int r = i / 205, p = i - r * 205;
                float2 v = *(const float2*)(xb + r * 410 + 2 * p);
                int dst = (p < 150) ? p : (p < 187 ? p + 2 : p + 5);
                pX[r][dst] = pk2(v.x, v.y);
            }
            for (int i = tid; i < 4 * 192; i += 512) {
                int r = i / 192, p = i - r * 192;
                float v0, v1; int c;
                if (p < 128) { c = 2 * p; v0 = sTc[r][c]; v1 = sTc[r][c + 1]; }
                else if (p < 160) { int j = 2 * (p - 128); c = 256 + j; v0 = sAc[r][j]; v1 = sAc[r][j + 1]; }
                else { int j = 2 * (p - 160); c = 320 + j; v0 = sVc[r][j]; v1 = sVc[r][j + 1]; }
                sCs[r][c] = v0; sCs[r][c + 1] = v1;
                pCs[r][p] = pk2(v0, v1);
            }
            __syncthreads();

            // ---- stage 2 ----
            {
                float acc[8] = {0.f, 0.f, 0.f, 0.f, 0.f, 0.f, 0.f, 0.f};
                gpart<2, 3>(acc, &pX[0][0], 150, 212, wsu + OFF_TWI + 4 * tid, 1024);
                gpart<2, 3>(acc, &pTh[0][0], 128, 128, wsu + OFF_TWI + 150L * 1024 + 4 * tid, 1024);
                float bb0 = t_b[2 * tid], bb1 = t_b[2 * tid + 1];
#pragma unroll
                for (int r = 0; r < 4; ++r) {
                    sZ[r][2 * tid] = acc[2 * r] + bb0;
                    sZ[r][2 * tid + 1] = acc[2 * r + 1] + bb1;
                }
            }
            if (tid < 256) {
                float acc[4] = {0.f, 0.f, 0.f, 0.f};
                gpart<1, 3>(acc, &pX[0][152], 38, 212, wsu + OFF_AWI + 2 * tid, 256);
                gpart<1, 3>(acc, &pAh[0][0], 32, 32, wsu + OFF_AWI + 38L * 256 + 2 * tid, 256);
                float b = a_b[tid];
#pragma unroll
                for (int r = 0; r < 4; ++r) sZa[r][tid] = acc[r] + b;
            } else {
                int st = tid - 256;
                float acc[4] = {0.f, 0.f, 0.f, 0.f};
                gpart<1, 3>(acc, &pX[0][192], 18, 212, wsu + OFF_VWI + 2 * st, 256);
                gpart<1, 3>(acc, &pVh[0][0], 32, 32, wsu + OFF_VWI + 18L * 256 + 2 * st, 256);
                float b = v_b[st];
#pragma unroll
                for (int r = 0; r < 4; ++r) sZv[r][st] = acc[r] + b;
            }
            __syncthreads();

            // ---- stage 3 ----
            {
                int j = tid & 255;
                for (int r = tid >> 8; r < 4; r += 2) {
                    float iv = sZ[r][j], fv = sZ[r][256 + j], gv = sZ[r][512 + j], ov = sZ[r][768 + j];
                    float c2 = sigm(fv) * sTc[r][j] + sigm(iv) * tanh_fast(gv);
                    float h2 = sigm(ov) * tanh_fast(c2);
                    sTc[r][j] = c2; sCs[r][384 + j] = c2;
                    float c2o = __shfl_xor(c2, 1), h2o = __shfl_xor(h2, 1);
                    if (!(j & 1)) {
                        pTh[r][j >> 1] = pk2(h2, h2o);
                        pCs[r][192 + (j >> 1)] = pk2(c2, c2o);
                    }
                }
                int cell = tid >> 8, r2 = (tid >> 6) & 3, j2 = tid & 63;
                if (cell == 0) {
                    float iv = sZa[r2][j2], fv = sZa[r2][64 + j2], gv = sZa[r2][128 + j2], ov = sZa[r2][192 + j2];
                    float c2 = sigm(fv) * sAc[r2][j2] + sigm(iv) * tanh_fast(gv);
                    float h2 = sigm(ov) * tanh_fast(c2);
                    sAc[r2][j2] = c2; sCs[r2][640 + j2] = c2;
                    float c2o = __shfl_xor(c2, 1), h2o = __shfl_xor(h2, 1);
                    if (!(j2 & 1)) {
                        pAh[r2][j2 >> 1] = pk2(h2, h2o);
                        pCs[r2][320 + (j2 >> 1)] = pk2(c2, c2o);
                    }
                } else {
                    float iv = sZv[r2][j2], fv = sZv[r2][64 + j2], gv = sZv[r2][128 + j2], ov = sZv[r2][192 + j2];
                    float c2 = sigm(fv) * sVc[r2][j2] + sigm(iv) * tanh_fast(gv);
                    float h2 = sigm(ov) * tanh_fast(c2);
                    sVc[r2][j2] = c2; sCs[r2][704 + j2] = c2;
                    float c2o = __shfl_xor(c2, 1), h2o = __shfl_xor(h2, 1);
                    if (!(j2 & 1)) {
                        pVh[r2][j2 >> 1] = pk2(h2, h2o);
                        pCs[r2][352 + (j2 >> 1)] = pk2(c2, c2o);
                    }
                }
            }
            __syncthreads();

            // ---- stage 4a: attn1-l1 split-K x2 ----
            {
                int half = tid >> 8, st = tid & 255;
                float acc[8] = {0.f, 0.f, 0.f, 0.f, 0.f, 0.f, 0.f, 0.f};
                gpart<2, 3>(acc, &pCs[0][half * 192], 192, 384,
                            wsu + OFF_A1W1 + (long)half * 192 * 512 + 4 * st, 512);
#pragma unroll
                for (int r = 0; r < 4; ++r) {
                    sPart[half][r][2 * st] = acc[2 * r];
                    sPart[half][r][2 * st + 1] = acc[2 * r + 1];
                }
            }
            __syncthreads();
            for (int i = tid; i < 1024; i += 512) {
                int r = i >> 8, cp = i & 255, c = 2 * cp;
                float v0 = fmaxf(sPart[0][r][c] + sPart[1][r][c] + a1b1[c], 0.f);
                float v1 = fmaxf(sPart[0][r][c + 1] + sPart[1][r][c + 1] + a1b1[c + 1], 0.f);
                pHid[r][cp] = pk2(v0, v1);
            }
            __syncthreads();

            // ---- stage 4b: attn1-l2 ----
            if (tid < 384) {
                float acc[8] = {0.f, 0.f, 0.f, 0.f, 0.f, 0.f, 0.f, 0.f};
                gpart<2, 3>(acc, &pHid[0][0], 256, 256, wsu + OFF_A1W2 + 4 * tid, 768);
                float bb0 = a1b2[2 * tid], bb1 = a1b2[2 * tid + 1];
#pragma unroll
                for (int r = 0; r < 4; ++r) {
                    sZ[r][2 * tid] = acc[2 * r] + bb0;
                    sZ[r][2 * tid + 1] = acc[2 * r + 1] + bb1;
                }
            }
            __syncthreads();

            // ---- stage 5: softmax + attended -> attq handoff + local pCs ----
            {
                int wv = tid >> 6, ln = tid & 63;
                if (wv < 4) {
                    float mx = -3.0e38f;
                    for (int i = ln; i < 768; i += 64) mx = fmaxf(mx, sZ[wv][i]);
                    for (int o = 32; o; o >>= 1) mx = fmaxf(mx, __shfl_xor(mx, o));
                    float sum = 0.f;
                    for (int i = ln; i < 768; i += 64) { float e = __expf(sZ[wv][i] - mx); sZ[wv][i] = e; sum += e; }
                    for (int o = 32; o; o >>= 1) sum += __shfl_xor(sum, o);
                    if (ln == 0) sRed[wv] = 1.f / sum;
                }
            }
            __syncthreads();
            {
                u64* dst = (u64*)(attq + ((long)(t & 3) * NBATCH + row0) * 384);
                for (int ii = tid; ii < 768; ii += 512) {
                    int base = 2 * ii;
                    int r = base / 384, p = base - r * 384, c = 2 * p;
                    float s = sRed[r];
                    u32 w0 = pk2(sZ[r][c] * s * sCs[r][c], sZ[r][c + 1] * s * sCs[r][c + 1]);
                    u32 w1 = pk2(sZ[r][c + 2] * s * sCs[r][c + 2], sZ[r][c + 3] * s * sCs[r][c + 3]);
                    pCs[r][p] = w0; pCs[r][p + 1] = w1;
                    ATOMIC_RLX_AG(dst + ii, (u64)w0 | ((u64)w1 << 32));
                }
            }
            __syncthreads();

            // ---- stage 5b: attn2-l1 K-half0 (rebalance) -> apq handoff ----
            {
                float acc[4] = {0.f, 0.f, 0.f, 0.f};
                gpart<1, 3>(acc, &pCs[0][0], 192, 384, wsu + OFF_A2W1 + 2 * tid, 512);
                u64* dst = apq + ((long)(t & 3) * NBATCH + row0) * 256;
#pragma unroll
                for (int r = 0; r < 4; ++r) {
                    float f1 = __shfl_xor(acc[r], 1);
                    if (!(tid & 1)) {
                        u64 v = (u64)__float_as_uint(acc[r]) | ((u64)__float_as_uint(f1) << 32);
                        ATOMIC_RLX_AG(dst + r * 256 + (tid >> 1), v);
                    }
                }
            }
            __syncthreads();
            if (tid == 0)
                __hip_atomic_store(flagA + g, t + 1, __ATOMIC_RELEASE, __HIP_MEMORY_SCOPE_AGENT);
        }

        // ---- A epilogue: partial output head (th/ah/vh) -> owp ----
        {
            float acc[4] = {0.f, 0.f, 0.f, 0.f};
            gpart<1, 3>(acc, &pTh[0][0], 128, 128, wsu + OFF_OW1 + 2 * tid, 512);
            gpart<1, 3>(acc, &pAh[0][0], 32, 32, wsu + OFF_OW1 + 128L * 512 + 2 * tid, 512);
            gpart<1, 3>(acc, &pVh[0][0], 32, 32, wsu + OFF_OW1 + 160L * 512 + 2 * tid, 512);
#pragma unroll
            for (int r = 0; r < 4; ++r)
                ATOMIC_RLX_AG(owp + (long)(row0 + r) * 512 + tid, __float_as_uint(acc[r]));
        }
        __syncthreads();
        if (tid == 0)
            __hip_atomic_store(flagA + g, 1000, __ATOMIC_RELEASE, __HIP_MEMORY_SCOPE_AGENT);

    } else {
        // ================= ROLE B =================
        for (int i = tid; i < 4 * 128; i += 512) {
            int r = i >> 7, j2 = i & 127, j = 2 * j2;
            float m0 = mem0[(row0 + r) * 256 + j], m1 = mem0[(row0 + r) * 256 + j + 1];
            sM[r][j] = m0; sM[r][j + 1] = m1;
            pM[r][j2] = pk2(m0, m1);
        }
        __syncthreads();

        for (int t = 0; t < T_STEPS_D; ++t) {
            if (tid == 0) {
                while (__hip_atomic_load(flagA + g, __ATOMIC_ACQUIRE,
                                         __HIP_MEMORY_SCOPE_AGENT) < t + 1)
                    __builtin_amdgcn_s_sleep(2);
            }
            __syncthreads();
            {   // copy attended -> pCs AND a2w1-half0 partials -> sPart[1]
                const u64* src = (const u64*)(attq + ((long)(t & 3) * NBATCH + row0) * 384);
                for (int ii = tid; ii < 768; ii += 512) {
                    u64 v = ATOMIC_LD_AG(src + ii);
                    int base = 2 * ii, r = base / 384, p = base - r * 384;
                    pCs[r][p] = (u32)v;
                    pCs[r][p + 1] = (u32)(v >> 32);
                }
                const u64* src2 = apq + ((long)(t & 3) * NBATCH + row0) * 256;
                for (int ii = tid; ii < 1024; ii += 512) {
                    u64 v = ATOMIC_LD_AG(src2 + ii);
                    int r = ii >> 8, cp = ii & 255;
                    sPart[1][r][2 * cp] = __uint_as_float((u32)v);
                    sPart[1][r][2 * cp + 1] = __uint_as_float((u32)(v >> 32));
                }
            }
            __syncthreads();
            if (tid == 0)
                __hip_atomic_store(flagB + g, t + 1, __ATOMIC_RELEASE, __HIP_MEMORY_SCOPE_AGENT);

            // ---- stage 6: a2w1-half1 -> sPart[0] ; gates-l1 -> pZ ----
            {
                float acc[4] = {0.f, 0.f, 0.f, 0.f};
                gpart<1, 3>(acc, &pCs[0][192], 192, 384,
                            wsu + OFF_A2W1 + 192L * 512 + 2 * tid, 512);
#pragma unroll
                for (int r = 0; r < 4; ++r) sPart[0][r][tid] = acc[r];
            }
            {
                float acc[8] = {0.f, 0.f, 0.f, 0.f, 0.f, 0.f, 0.f, 0.f};
                gpart<2, 3>(acc, &pCs[0][0], 384, 384, wsu + OFF_GW1 + 4 * tid, 1024);
                gpart<2, 3>(acc, &pM[0][0], 128, 128, wsu + OFF_GW1 + 384L * 1024 + 4 * tid, 1024);
                float bb0 = wsf[2 * tid], bb1 = wsf[2 * tid + 1];
#pragma unroll
                for (int r = 0; r < 4; ++r) {
                    float v0 = fmaxf(acc[2 * r] + bb0, 0.f);
                    float v1 = fmaxf(acc[2 * r + 1] + bb1, 0.f);
                    pZ[r][tid] = pk2(v0, v1);
                }
            }
            __syncthreads();
            for (int i = tid; i < 1024; i += 512) {   // combine attn2-l1 -> pHid
                int r = i >> 8, cp = i & 255, c = 2 * cp;
                float v0 = fmaxf(sPart[1][r][c] + sPart[0][r][c] + a2b1[c], 0.f);
                float v1 = fmaxf(sPart[1][r][c + 1] + sPart[0][r][c + 1] + a2b1[c + 1], 0.f);
                pHid[r][cp] = pk2(v0, v1);
            }
            __syncthreads();

            // ---- stage 7: gates-l2 split-K -> sPart ; attn2-l2 -> sCp ----
            {
                int half = tid >> 8, st = tid & 255;
                float acc[8] = {0.f, 0.f, 0.f, 0.f, 0.f, 0.f, 0.f, 0.f};
                const u32* actb = &pZ[0][(st >= 128 ? 256 : 0) + half * 128];
                gpart<2, 3>(acc, actb, 128, 512,
                            wsu + OFF_GW2 + (long)half * 128 * 512 + 4 * st, 512);
#pragma unroll
                for (int r = 0; r < 4; ++r) {
                    sPart[half][r][2 * st] = acc[2 * r];
                    sPart[half][r][2 * st + 1] = acc[2 * r + 1];
                }
            }
            {
                int kh = tid >> 8, col = tid & 255;
                float acc[4] = {0.f, 0.f, 0.f, 0.f};
                gpart<1, 3>(acc, &pHid[0][kh * 128], 128, 256,
                            wsu + OFF_A2W2 + (long)kh * 128 * 256 + 2 * col, 256);
#pragma unroll
                for (int r = 0; r < 4; ++r) sCp[kh][r][col] = acc[r];
            }
            __syncthreads();

            // ---- stage 8: memory update ----
            {
                int j = tid & 255;
                for (int r = tid >> 8; r < 4; r += 2) {
                    float g1raw = sPart[0][r][j] + sPart[1][r][j] + wsf[1024 + j];
                    float g2raw = sPart[0][r][256 + j] + sPart[1][r][256 + j] + wsf[1280 + j];
                    float g1v = sigm(g1raw);
                    float g2v = sigm(g2raw);
                    float ch = tanh_fast(sCp[0][r][j] + sCp[1][r][j] + a2b2[j]);
                    float m2 = g1v * sM[r][j] + g2v * ch;
                    sM[r][j] = m2;
                    float m2o = __shfl_xor(m2, 1);
                    if (!(j & 1)) pM[r][j >> 1] = pk2(m2, m2o);
                }
            }
            __syncthreads();
        }

        // ---- B epilogue ----
        {
            float acc[4] = {0.f, 0.f, 0.f, 0.f};
            gpart<1, 3>(acc, &pM[0][0], 128, 128, wsu + OFF_OW1 + 192L * 512 + 2 * tid, 512);
            if (tid == 0) {
                while (__hip_atomic_load(flagA + g, __ATOMIC_ACQUIRE,
                                         __HIP_MEMORY_SCOPE_AGENT) < 1000)
                    __builtin_amdgcn_s_sleep(2);
            }
            __syncthreads();
            float wv2 = ow2[tid], b = ob1[tid];
            float pr[4];
#pragma unroll
            for (int r = 0; r < 4; ++r) {
                float ap = __uint_as_float(ATOMIC_LD_AG(owp + (long)(row0 + r) * 512 + tid));
                float h = fmaxf(acc[r] + ap + b, 0.f);
                pr[r] = h * wv2;
            }
#pragma unroll
            for (int o = 32; o; o >>= 1) {
#pragma unroll
                for (int r = 0; r < 4; ++r) pr[r] += __shfl_xor(pr[r], o);
            }
            int wvid = tid >> 6, ln = tid & 63;
            if (ln == 0) {
#pragma unroll
                for (int r = 0; r < 4; ++r) sRed2[wvid][r] = pr[r];
            }
            __syncthreads();
            if (tid < 4) {
                float s = 0.f;
#pragma unroll
                for (int w = 0; w < 8; ++w) s += sRed2[w][tid];
                out[row0 + tid] = s + ob2[0];
            }
        }
    }
}

extern "C" void kernel_launch(void* const* d_in, const int* in_sizes, int n_in,
                              void* d_out, int out_size, void* d_ws, size_t ws_size,
                              hipStream_t stream)
{
    const float* x_p  = (const float*)d_in[0];
    const float* c_t  = (const float*)d_in[1];
    const float* c_a  = (const float*)d_in[2];
    const float* c_v  = (const float*)d_in[3];
    const float* memp = (const float*)d_in[4];

    u32* wsu = (u32*)d_ws;
    float* wsf = (float*)((char*)d_ws + (size_t)U32_TOTAL * 4);

    // zero AWI pad region + sync flags (both re-run every graph replay)
    hipMemsetAsync((char*)d_ws + (size_t)OFF_AWI * 4, 0, (size_t)(OFF_VWI - OFF_AWI) * 4, stream);
    hipMemsetAsync((char*)d_ws + (size_t)FLAGS_OFF * 4, 0, 1024, stream);

    auto T = [&](const void* src, long off, int N, int K, int strideU, int rowOffK, int colOff) {
        long total = (long)N * K;
        int blocks = (int)((total + 255) / 256);
        hipLaunchKernelGGL(k_transpose, dim3(blocks), dim3(256), 0, stream,
                           (const float*)src, (unsigned short*)(wsu + off), N, K, strideU, rowOffK, colOff);
    };
    T(d_in[5],  OFF_TWI,  1024, 300, 1024, 0,   0);   // t_Wi
    T(d_in[6],  OFF_TWI,  1024, 256, 1024, 300, 0);   // t_Wh
    T(d_in[8],  OFF_AWI,  256,  74,  256,  0,   0);   // a_Wi (74,75 zero pad)
    T(d_in[9],  OFF_AWI,  256,  64,  256,  76,  0);   // a_Wh
    T(d_in[11], OFF_VWI,  256,  36,  256,  0,   0);   // v_Wi
    T(d_in[12], OFF_VWI,  256,  64,  256,  36,  0);   // v_Wh
    T(d_in[14], OFF_A1W1, 512,  768, 512,  0,   0);   // attn1_w1
    T(d_in[16], OFF_A1W2, 768,  512, 768,  0,   0);   // attn1_w2
    T(d_in[18], OFF_A2W1, 512,  768, 512,  0,   0);   // attn2_w1
    T(d_in[20], OFF_A2W2, 256,  512, 256,  0,   0);   // attn2_w2
    T(d_in[22], OFF_GW1,  512, 1024, 1024, 0,   0);   // g1_w1
    T(d_in[26], OFF_GW1,  512, 1024, 1024, 0,   512); // g2_w1
    T(d_in[24], OFF_GW2,  256,  512, 512,  0,   0);   // g1_w2
    T(d_in[28], OFF_GW2,  256,  512, 512,  0,   256); // g2_w2
    T(d_in[30], OFF_OW1,  512,  640, 512,  0,   0);   // out_w1

    hipLaunchKernelGGL(k_packbias, dim3(6), dim3(256), 0, stream,
                       (const float*)d_in[23], (const float*)d_in[27],
                       (const float*)d_in[25], (const float*)d_in[29], wsf);

    hipLaunchKernelGGL(fused_rnn, dim3(256), dim3(512), 0, stream,
                       x_p, c_t, c_a, c_v, memp,
                       (const float*)d_in[7],  (const float*)d_in[10], (const float*)d_in[13],
                       (const float*)d_in[15], (const float*)d_in[17],
                       (const float*)d_in[19], (const float*)d_in[21],
                       (const float*)d_in[31], (const float*)d_in[32], (const float*)d_in[33],
                       wsu, wsf, wsu, (float*)d_out);
}

// Round 17
// 23474.252 us; speedup vs baseline: 1.2212x; 1.2212x over previous
//
#include <hip/hip_runtime.h>
#include <hip/hip_bf16.h>
#include <hip/hip_fp16.h>

typedef unsigned int u32;
typedef unsigned long long u64;
typedef __fp16 h2t __attribute__((ext_vector_type(2)));

// ---------------- dims ----------------
#define T_STEPS_D 128
#define NBATCH 512

// ws layout (u32 element offsets). Weights f16, QUAD-packed:
// quad q (= k-pairs 2q,2q+1), column n: u32[q*2N + 2n + s], s = pair slot (0/1).
#define OFF_TWI   0L         // pairs 278 (150 t_Wi + 128 t_Wh), N=1024
#define OFF_AWI   284672L    // pairs 70 (38 a_Wi [2 zero-pad rows] + 32 a_Wh), N=256
#define OFF_VWI   302592L    // pairs 50 (18 v_Wi + 32 v_Wh), N=256
#define OFF_A1W1  315392L    // pairs 384, N=512
#define OFF_A1W2  512000L    // pairs 256, N=768
#define OFF_A2W1  708608L    // pairs 384, N=512 (K-half0 by role A, half1 by B)
#define OFF_A2W2  905216L    // pairs 256, N=256
#define OFF_GW1   970752L    // pairs 512, N=1024
#define OFF_GW2   1495040L   // pairs 256, N=512
#define OFF_OW1   1626112L   // pairs 320, N=512
#define U32_TOTAL 1789952L   // fp32 packed biases follow (1536 floats)
// pipeline comm regions (u32 offsets)
#define FLAGS_OFF 1791744L   // flagA[128], flagB[128] (memset each launch)
#define ATTQ_OFF  1792000L   // u32: 4 bufs x 512 rows x 384 pairs (8B aligned)
#define OWP_OFF   2578432L   // f32 bits: 512 rows x 512
#define APQ_OFF   2840576L   // u64-packed f32 pairs: 4 bufs x 512 rows x 256
#define ATOMIC_RLX_AG(p, v) __hip_atomic_store((p), (v), __ATOMIC_RELAXED, __HIP_MEMORY_SCOPE_AGENT)
#define ATOMIC_LD_AG(p)     __hip_atomic_load((p), __ATOMIC_RELAXED, __HIP_MEMORY_SCOPE_AGENT)

__device__ __forceinline__ float sigm(float x) { return 1.f / (1.f + __expf(-x)); }
__device__ __forceinline__ float tanh_fast(float x) {
    float e = __expf(2.f * x);
    return 1.f - 2.f / (e + 1.f);
}
__device__ __forceinline__ float dot2(u32 a, u32 b, float c) {
    union { u32 u; h2t h; } x, y; x.u = a; y.u = b;
#if __has_builtin(__builtin_amdgcn_fdot2)
    return __builtin_amdgcn_fdot2(x.h, y.h, c, false);
#else
    c += (float)x.h[0] * (float)y.h[0];
    c += (float)x.h[1] * (float)y.h[1];
    return c;
#endif
}
__device__ __forceinline__ u32 pk2(float a, float b) {
    union { h2t h; u32 u; } z;
    z.h = __builtin_amdgcn_cvt_pkrtz(a, b);
    return z.u;
}

// ---- weight block loads: one block = 8 k-pairs = 4 quads ----
__device__ __forceinline__ void gp_load1(u32* buf, const u32* __restrict__ wp, int N) {
#pragma unroll
    for (int q = 0; q < 4; ++q) {
        uint2 v = *(const uint2*)(wp + q * 2 * N);
        buf[2 * q] = v.x; buf[2 * q + 1] = v.y;
    }
}
__device__ __forceinline__ void gp_load2(u32* buf, const u32* __restrict__ wp, int N) {
#pragma unroll
    for (int q = 0; q < 4; ++q) {
        uint4 v = *(const uint4*)(wp + q * 2 * N);
        buf[4 * q] = v.x; buf[4 * q + 1] = v.y; buf[4 * q + 2] = v.z; buf[4 * q + 3] = v.w;
    }
}

// compute one block: 8 k-pairs x 4 rows x NC cols. acc[NC*r+c].
template<int NC>
__device__ __forceinline__ void gp_comp(float* acc, const u32* __restrict__ a, int stA,
                                        int kb, const u32* buf) {
#pragma unroll
    for (int r = 0; r < 4; ++r) {
        uint4 xa = *(const uint4*)(a + r * stA + kb);
        uint4 xb = *(const uint4*)(a + r * stA + kb + 4);
        u32 av[8] = {xa.x, xa.y, xa.z, xa.w, xb.x, xb.y, xb.z, xb.w};
#pragma unroll
        for (int p = 0; p < 8; ++p) {
            if constexpr (NC == 1) {
                acc[r] = dot2(buf[p], av[p], acc[r]);
            } else {
                acc[2 * r]     = dot2(buf[4 * (p >> 1) + (p & 1)],     av[p], acc[2 * r]);
                acc[2 * r + 1] = dot2(buf[4 * (p >> 1) + 2 + (p & 1)], av[p], acc[2 * r + 1]);
            }
        }
    }
}

// acc[NC*r+c] += sum_k a[r][k] * W[k][col_base+c]. Register prefetch pipeline.
// NC=2 MUST stay DEPTH<=2 under the 128-VGPR cap (R16: DEPTH=3 spilled, 29ms).
template<int NC, int DEPTH>
__device__ __forceinline__ void gpart(float* acc, const u32* __restrict__ a, int k2, int stA,
                                      const u32* __restrict__ w, int N)
{
    const int nb = k2 >> 3;
    u32 b0[NC * 8], b1[NC * 8], b2[NC * 8];
#define GLOAD(B, P) do { if constexpr (NC == 1) gp_load1(B, w + (long)(P) * 8 * N, N); \
                         else gp_load2(B, w + (long)(P) * 8 * N, N); } while (0)
    if (nb > 0) GLOAD(b0, 0);
    if (DEPTH > 1 && nb > 1) GLOAD(b1, 1);
    if (DEPTH > 2 && nb > 2) GLOAD(b2, 2);
    int i = 0;
    while (i < nb) {
        gp_comp<NC>(acc, a, stA, i * 8, b0);
        if (i + DEPTH < nb) GLOAD(b0, i + DEPTH);
        ++i; if (i >= nb) break;
        gp_comp<NC>(acc, a, stA, i * 8, b1);
        if (i + DEPTH < nb) GLOAD(b1, i + DEPTH);
        ++i; if (i >= nb) break;
        if (DEPTH > 2) {
            gp_comp<NC>(acc, a, stA, i * 8, b2);
            if (i + DEPTH < nb) GLOAD(b2, i + DEPTH);
            ++i;
        }
    }
#undef GLOAD
    for (int p = nb * 8; p < k2; ++p) {     // tail (<8 pairs)
        const u32* wp = w + (long)(p >> 1) * 2 * N + (p & 1);
#pragma unroll
        for (int r = 0; r < 4; ++r) {
            u32 aa = a[r * stA + p];
            if constexpr (NC == 1) {
                acc[r] = dot2(wp[0], aa, acc[r]);
            } else {
                acc[2 * r]     = dot2(wp[0], aa, acc[2 * r]);
                acc[2 * r + 1] = dot2(wp[2], aa, acc[2 * r + 1]);
            }
        }
    }
}

// -------- prologue kernels --------
__global__ void k_transpose(const float* __restrict__ src, unsigned short* __restrict__ dst,
                            int N, int K, int strideU, int rowOffK, int colOff)
{
    long i = (long)blockIdx.x * 256 + threadIdx.x;
    if (i >= (long)N * K) return;
    int n = (int)(i / K);
    int k = (int)(i - (long)n * K);
    __half h = __float2half(src[i]);
    long kk = k + rowOffK;
    long idx32 = (kk >> 2) * 2L * strideU + 2L * (colOff + n) + ((kk >> 1) & 1);
    dst[idx32 * 2 + (kk & 1)] = __half_as_ushort(h);
}

__global__ void k_packbias(const float* __restrict__ g1b1, const float* __restrict__ g2b1,
                           const float* __restrict__ g1b2, const float* __restrict__ g2b2,
                           float* __restrict__ gb)
{
    int i = blockIdx.x * 256 + threadIdx.x;
    if (i < 512) gb[i] = g1b1[i];
    else if (i < 1024) gb[i] = g2b1[i - 512];
    else if (i < 1280) gb[i] = g1b2[i - 1024];
    else if (i < 1536) gb[i] = g2b2[i - 1280];
}

// -------- main: 256 WGs x 512 threads; role split by XCD (bid%8) --------
// A (XCD 0-3): LSTMs + attn1 + softmax + attended + a2w1-half0  (~3.24 MB/step)
// B (XCD 4-7): a2w1-half1 + a2w2 + gates + memory               (~3.28 MB/step)
// Cross-XCD payloads via AGENT-scope atomics (R14 lesson). Bare launch_bounds(512)
// is the ONLY config that holds VGPR=128 without spilling (R6/7/8/12/16 lessons).
__global__ __launch_bounds__(512)
void fused_rnn(const float* __restrict__ x_p,
               const float* __restrict__ c_t0, const float* __restrict__ c_a0,
               const float* __restrict__ c_v0, const float* __restrict__ mem0,
               const float* __restrict__ t_b, const float* __restrict__ a_b,
               const float* __restrict__ v_b,
               const float* __restrict__ a1b1, const float* __restrict__ a1b2,
               const float* __restrict__ a2b1, const float* __restrict__ a2b2,
               const float* __restrict__ ob1, const float* __restrict__ ow2,
               const float* __restrict__ ob2,
               const u32* __restrict__ wsu, const float* __restrict__ wsf,
               u32* wsrw,
               float* __restrict__ out)
{
    const int tid = threadIdx.x;
    const int xcd = (int)blockIdx.x & 7;
    const bool isA = xcd < 4;
    const int g = ((int)blockIdx.x >> 3) * 4 + (xcd & 3);
    const int row0 = g * 4;

    int* flagA = (int*)(wsrw + FLAGS_OFF);
    int* flagB = flagA + 128;
    u32* attq = wsrw + ATTQ_OFF;
    u32* owp = wsrw + OWP_OFF;
    u64* apq = (u64*)(wsrw + APQ_OFF);

    // fp32 buffers
    __shared__ alignas(16) float sZ[4][1024];
    __shared__ alignas(16) float sZa[4][256];
    __shared__ alignas(16) float sZv[4][256];
    __shared__ alignas(16) float sTc[4][256];
    __shared__ alignas(16) float sAc[4][64];
    __shared__ alignas(16) float sVc[4][64];
    __shared__ alignas(16) float sM[4][256];
    __shared__ alignas(16) float sCs[4][768];
    __shared__ alignas(16) float sCp[2][4][256];
    __shared__ alignas(16) float sHid[4][512];
    __shared__ alignas(16) float sPart[2][4][512];
    // packed f16-pair buffers
    __shared__ alignas(16) u32 pX[4][212];
    __shared__ alignas(16) u32 pCs[4][384];
    __shared__ alignas(16) u32 pTh[4][128];
    __shared__ alignas(16) u32 pAh[4][32];
    __shared__ alignas(16) u32 pVh[4][32];
    __shared__ alignas(16) u32 pM[4][128];
    __shared__ alignas(16) u32 pHid[4][256];
    __shared__ alignas(16) u32 pZ[4][512];
    __shared__ float sRed[4];
    __shared__ float sRed2[8][4];

    if (isA) {
        // ================= ROLE A =================
        for (int i = tid; i < 4 * 128; i += 512) {
            int r = i >> 7, j2 = i & 127, j = 2 * j2;
            sTc[r][j] = c_t0[(row0 + r) * 256 + j];
            sTc[r][j + 1] = c_t0[(row0 + r) * 256 + j + 1];
            pTh[r][j2] = 0u;
        }
        for (int i = tid; i < 4 * 32; i += 512) {
            int r = i >> 5, j2 = i & 31, j = 2 * j2;
            sAc[r][j] = c_a0[(row0 + r) * 64 + j]; sAc[r][j + 1] = c_a0[(row0 + r) * 64 + j + 1];
            sVc[r][j] = c_v0[(row0 + r) * 64 + j]; sVc[r][j + 1] = c_v0[(row0 + r) * 64 + j + 1];
            pAh[r][j2] = 0u; pVh[r][j2] = 0u;
        }
        if (tid < 12) pX[tid / 3][189 + tid % 3] = 0u;
        __syncthreads();

        for (int t = 0; t < T_STEPS_D; ++t) {
            if (t >= 4) {   // quad-buffer reuse guard (attq + apq)
                if (tid == 0) {
                    while (__hip_atomic_load(flagB + g, __ATOMIC_ACQUIRE,
                                             __HIP_MEMORY_SCOPE_AGENT) < t - 3)
                        __builtin_amdgcn_s_sleep(2);
                }
                __syncthreads();
            }
            // ---- stage 1 ----
            const float* xb = x_p + ((long)t * NBATCH + row0) * 410;
            for (int i = tid; i < 4 * 205; i += 512) {
                int r = i / 205, p = i - r * 205;
                float2 v = *(const float2*)(xb + r * 410 + 2 * p);
                int dst = (p < 150) ? p : (p < 187 ? p + 2 : p + 5);
                pX[r][dst] = pk2(v.x, v.y);
            }
            for (int i = tid; i < 4 * 192; i += 512) {
                int r = i / 192, p = i - r * 192;
                float v0, v1; int c;
                if (p < 128) { c = 2 * p; v0 = sTc[r][c]; v1 = sTc[r][c + 1]; }
                else if (p < 160) { int j = 2 * (p - 128); c = 256 + j; v0 = sAc[r][j]; v1 = sAc[r][j + 1]; }
                else { int j = 2 * (p - 160); c = 320 + j; v0 = sVc[r][j]; v1 = sVc[r][j + 1]; }
                sCs[r][c] = v0; sCs[r][c + 1] = v1;
                pCs[r][p] = pk2(v0, v1);
            }
            __syncthreads();

            // ---- stage 2 ----
            {
                float acc[8] = {0.f, 0.f, 0.f, 0.f, 0.f, 0.f, 0.f, 0.f};
                gpart<2, 2>(acc, &pX[0][0], 150, 212, wsu + OFF_TWI + 4 * tid, 1024);
                gpart<2, 2>(acc, &pTh[0][0], 128, 128, wsu + OFF_TWI + 150L * 1024 + 4 * tid, 1024);
                float bb0 = t_b[2 * tid], bb1 = t_b[2 * tid + 1];
#pragma unroll
                for (int r = 0; r < 4; ++r) {
                    sZ[r][2 * tid] = acc[2 * r] + bb0;
                    sZ[r][2 * tid + 1] = acc[2 * r + 1] + bb1;
                }
            }
            if (tid < 256) {
                float acc[4] = {0.f, 0.f, 0.f, 0.f};
                gpart<1, 3>(acc, &pX[0][152], 38, 212, wsu + OFF_AWI + 2 * tid, 256);
                gpart<1, 3>(acc, &pAh[0][0], 32, 32, wsu + OFF_AWI + 38L * 256 + 2 * tid, 256);
                float b = a_b[tid];
#pragma unroll
                for (int r = 0; r < 4; ++r) sZa[r][tid] = acc[r] + b;
            } else {
                int st = tid - 256;
                float acc[4] = {0.f, 0.f, 0.f, 0.f};
                gpart<1, 3>(acc, &pX[0][192], 18, 212, wsu + OFF_VWI + 2 * st, 256);
                gpart<1, 3>(acc, &pVh[0][0], 32, 32, wsu + OFF_VWI + 18L * 256 + 2 * st, 256);
                float b = v_b[st];
#pragma unroll
                for (int r = 0; r < 4; ++r) sZv[r][st] = acc[r] + b;
            }
            __syncthreads();

            // ---- stage 3 ----
            {
                int j = tid & 255;
                for (int r = tid >> 8; r < 4; r += 2) {
                    float iv = sZ[r][j], fv = sZ[r][256 + j], gv = sZ[r][512 + j], ov = sZ[r][768 + j];
                    float c2 = sigm(fv) * sTc[r][j] + sigm(iv) * tanh_fast(gv);
                    float h2 = sigm(ov) * tanh_fast(c2);
                    sTc[r][j] = c2; sCs[r][384 + j] = c2;
                    float c2o = __shfl_xor(c2, 1), h2o = __shfl_xor(h2, 1);
                    if (!(j & 1)) {
                        pTh[r][j >> 1] = pk2(h2, h2o);
                        pCs[r][192 + (j >> 1)] = pk2(c2, c2o);
                    }
                }
                int cell = tid >> 8, r2 = (tid >> 6) & 3, j2 = tid & 63;
                if (cell == 0) {
                    float iv = sZa[r2][j2], fv = sZa[r2][64 + j2], gv = sZa[r2][128 + j2], ov = sZa[r2][192 + j2];
                    float c2 = sigm(fv) * sAc[r2][j2] + sigm(iv) * tanh_fast(gv);
                    float h2 = sigm(ov) * tanh_fast(c2);
                    sAc[r2][j2] = c2; sCs[r2][640 + j2] = c2;
                    float c2o = __shfl_xor(c2, 1), h2o = __shfl_xor(h2, 1);
                    if (!(j2 & 1)) {
                        pAh[r2][j2 >> 1] = pk2(h2, h2o);
                        pCs[r2][320 + (j2 >> 1)] = pk2(c2, c2o);
                    }
                } else {
                    float iv = sZv[r2][j2], fv = sZv[r2][64 + j2], gv = sZv[r2][128 + j2], ov = sZv[r2][192 + j2];
                    float c2 = sigm(fv) * sVc[r2][j2] + sigm(iv) * tanh_fast(gv);
                    float h2 = sigm(ov) * tanh_fast(c2);
                    sVc[r2][j2] = c2; sCs[r2][704 + j2] = c2;
                    float c2o = __shfl_xor(c2, 1), h2o = __shfl_xor(h2, 1);
                    if (!(j2 & 1)) {
                        pVh[r2][j2 >> 1] = pk2(h2, h2o);
                        pCs[r2][352 + (j2 >> 1)] = pk2(c2, c2o);
                    }
                }
            }
            __syncthreads();

            // ---- stage 4a: attn1-l1 split-K x2 ----
            {
                int half = tid >> 8, st = tid & 255;
                float acc[8] = {0.f, 0.f, 0.f, 0.f, 0.f, 0.f, 0.f, 0.f};
                gpart<2, 2>(acc, &pCs[0][half * 192], 192, 384,
                            wsu + OFF_A1W1 + (long)half * 192 * 512 + 4 * st, 512);
#pragma unroll
                for (int r = 0; r < 4; ++r) {
                    sPart[half][r][2 * st] = acc[2 * r];
                    sPart[half][r][2 * st + 1] = acc[2 * r + 1];
                }
            }
            __syncthreads();
            for (int i = tid; i < 1024; i += 512) {
                int r = i >> 8, cp = i & 255, c = 2 * cp;
                float v0 = fmaxf(sPart[0][r][c] + sPart[1][r][c] + a1b1[c], 0.f);
                float v1 = fmaxf(sPart[0][r][c + 1] + sPart[1][r][c + 1] + a1b1[c + 1], 0.f);
                pHid[r][cp] = pk2(v0, v1);
            }
            __syncthreads();

            // ---- stage 4b: attn1-l2 ----
            if (tid < 384) {
                float acc[8] = {0.f, 0.f, 0.f, 0.f, 0.f, 0.f, 0.f, 0.f};
                gpart<2, 2>(acc, &pHid[0][0], 256, 256, wsu + OFF_A1W2 + 4 * tid, 768);
                float bb0 = a1b2[2 * tid], bb1 = a1b2[2 * tid + 1];
#pragma unroll
                for (int r = 0; r < 4; ++r) {
                    sZ[r][2 * tid] = acc[2 * r] + bb0;
                    sZ[r][2 * tid + 1] = acc[2 * r + 1] + bb1;
                }
            }
            __syncthreads();

            // ---- stage 5: softmax + attended -> attq handoff + local pCs ----
            {
                int wv = tid >> 6, ln = tid & 63;
                if (wv < 4) {
                    float mx = -3.0e38f;
                    for (int i = ln; i < 768; i += 64) mx = fmaxf(mx, sZ[wv][i]);
                    for (int o = 32; o; o >>= 1) mx = fmaxf(mx, __shfl_xor(mx, o));
                    float sum = 0.f;
                    for (int i = ln; i < 768; i += 64) { float e = __expf(sZ[wv][i] - mx); sZ[wv][i] = e; sum += e; }
                    for (int o = 32; o; o >>= 1) sum += __shfl_xor(sum, o);
                    if (ln == 0) sRed[wv] = 1.f / sum;
                }
            }
            __syncthreads();
            {
                u64* dst = (u64*)(attq + ((long)(t & 3) * NBATCH + row0) * 384);
                for (int ii = tid; ii < 768; ii += 512) {
                    int base = 2 * ii;
                    int r = base / 384, p = base - r * 384, c = 2 * p;
                    float s = sRed[r];
                    u32 w0 = pk2(sZ[r][c] * s * sCs[r][c], sZ[r][c + 1] * s * sCs[r][c + 1]);
                    u32 w1 = pk2(sZ[r][c + 2] * s * sCs[r][c + 2], sZ[r][c + 3] * s * sCs[r][c + 3]);
                    pCs[r][p] = w0; pCs[r][p + 1] = w1;
                    ATOMIC_RLX_AG(dst + ii, (u64)w0 | ((u64)w1 << 32));
                }
            }
            __syncthreads();

            // ---- stage 5b: attn2-l1 K-half0 (rebalance) -> apq handoff ----
            {
                float acc[4] = {0.f, 0.f, 0.f, 0.f};
                gpart<1, 3>(acc, &pCs[0][0], 192, 384, wsu + OFF_A2W1 + 2 * tid, 512);
                u64* dst = apq + ((long)(t & 3) * NBATCH + row0) * 256;
#pragma unroll
                for (int r = 0; r < 4; ++r) {
                    float f1 = __shfl_xor(acc[r], 1);
                    if (!(tid & 1)) {
                        u64 v = (u64)__float_as_uint(acc[r]) | ((u64)__float_as_uint(f1) << 32);
                        ATOMIC_RLX_AG(dst + r * 256 + (tid >> 1), v);
                    }
                }
            }
            __syncthreads();
            if (tid == 0)
                __hip_atomic_store(flagA + g, t + 1, __ATOMIC_RELEASE, __HIP_MEMORY_SCOPE_AGENT);
        }

        // ---- A epilogue: partial output head (th/ah/vh) -> owp ----
        {
            float acc[4] = {0.f, 0.f, 0.f, 0.f};
            gpart<1, 3>(acc, &pTh[0][0], 128, 128, wsu + OFF_OW1 + 2 * tid, 512);
            gpart<1, 3>(acc, &pAh[0][0], 32, 32, wsu + OFF_OW1 + 128L * 512 + 2 * tid, 512);
            gpart<1, 3>(acc, &pVh[0][0], 32, 32, wsu + OFF_OW1 + 160L * 512 + 2 * tid, 512);
#pragma unroll
            for (int r = 0; r < 4; ++r)
                ATOMIC_RLX_AG(owp + (long)(row0 + r) * 512 + tid, __float_as_uint(acc[r]));
        }
        __syncthreads();
        if (tid == 0)
            __hip_atomic_store(flagA + g, 1000, __ATOMIC_RELEASE, __HIP_MEMORY_SCOPE_AGENT);

    } else {
        // ================= ROLE B =================
        for (int i = tid; i < 4 * 128; i += 512) {
            int r = i >> 7, j2 = i & 127, j = 2 * j2;
            float m0 = mem0[(row0 + r) * 256 + j], m1 = mem0[(row0 + r) * 256 + j + 1];
            sM[r][j] = m0; sM[r][j + 1] = m1;
            pM[r][j2] = pk2(m0, m1);
        }
        __syncthreads();

        for (int t = 0; t < T_STEPS_D; ++t) {
            if (tid == 0) {
                while (__hip_atomic_load(flagA + g, __ATOMIC_ACQUIRE,
                                         __HIP_MEMORY_SCOPE_AGENT) < t + 1)
                    __builtin_amdgcn_s_sleep(2);
            }
            __syncthreads();
            {   // copy attended -> pCs AND a2w1-half0 partials -> sPart[1]
                const u64* src = (const u64*)(attq + ((long)(t & 3) * NBATCH + row0) * 384);
                for (int ii = tid; ii < 768; ii += 512) {
                    u64 v = ATOMIC_LD_AG(src + ii);
                    int base = 2 * ii, r = base / 384, p = base - r * 384;
                    pCs[r][p] = (u32)v;
                    pCs[r][p + 1] = (u32)(v >> 32);
                }
                const u64* src2 = apq + ((long)(t & 3) * NBATCH + row0) * 256;
                for (int ii = tid; ii < 1024; ii += 512) {
                    u64 v = ATOMIC_LD_AG(src2 + ii);
                    int r = ii >> 8, cp = ii & 255;
                    sPart[1][r][2 * cp] = __uint_as_float((u32)v);
                    sPart[1][r][2 * cp + 1] = __uint_as_float((u32)(v >> 32));
                }
            }
            __syncthreads();
            if (tid == 0)
                __hip_atomic_store(flagB + g, t + 1, __ATOMIC_RELEASE, __HIP_MEMORY_SCOPE_AGENT);

            // ---- stage 6: a2w1-half1 -> sPart[0] ; gates-l1 -> pZ ----
            {
                float acc[4] = {0.f, 0.f, 0.f, 0.f};
                gpart<1, 3>(acc, &pCs[0][192], 192, 384,
                            wsu + OFF_A2W1 + 192L * 512 + 2 * tid, 512);
#pragma unroll
                for (int r = 0; r < 4; ++r) sPart[0][r][tid] = acc[r];
            }
            {
                float acc[8] = {0.f, 0.f, 0.f, 0.f, 0.f, 0.f, 0.f, 0.f};
                gpart<2, 2>(acc, &pCs[0][0], 384, 384, wsu + OFF_GW1 + 4 * tid, 1024);
                gpart<2, 2>(acc, &pM[0][0], 128, 128, wsu + OFF_GW1 + 384L * 1024 + 4 * tid, 1024);
                float bb0 = wsf[2 * tid], bb1 = wsf[2 * tid + 1];
#pragma unroll
                for (int r = 0; r < 4; ++r) {
                    float v0 = fmaxf(acc[2 * r] + bb0, 0.f);
                    float v1 = fmaxf(acc[2 * r + 1] + bb1, 0.f);
                    pZ[r][tid] = pk2(v0, v1);
                }
            }
            __syncthreads();
            for (int i = tid; i < 1024; i += 512) {   // combine attn2-l1 -> pHid
                int r = i >> 8, cp = i & 255, c = 2 * cp;
                float v0 = fmaxf(sPart[1][r][c] + sPart[0][r][c] + a2b1[c], 0.f);
                float v1 = fmaxf(sPart[1][r][c + 1] + sPart[0][r][c + 1] + a2b1[c + 1], 0.f);
                pHid[r][cp] = pk2(v0, v1);
            }
            __syncthreads();

            // ---- stage 7: gates-l2 split-K -> sPart ; attn2-l2 -> sCp ----
            {
                int half = tid >> 8, st = tid & 255;
                float acc[8] = {0.f, 0.f, 0.f, 0.f, 0.f, 0.f, 0.f, 0.f};
                const u32* actb = &pZ[0][(st >= 128 ? 256 : 0) + half * 128];
                gpart<2, 2>(acc, actb, 128, 512,
                            wsu + OFF_GW2 + (long)half * 128 * 512 + 4 * st, 512);
#pragma unroll
                for (int r = 0; r < 4; ++r) {
                    sPart[half][r][2 * st] = acc[2 * r];
                    sPart[half][r][2 * st + 1] = acc[2 * r + 1];
                }
            }
            {
                int kh = tid >> 8, col = tid & 255;
                float acc[4] = {0.f, 0.f, 0.f, 0.f};
                gpart<1, 3>(acc, &pHid[0][kh * 128], 128, 256,
                            wsu + OFF_A2W2 + (long)kh * 128 * 256 + 2 * col, 256);
#pragma unroll
                for (int r = 0; r < 4; ++r) sCp[kh][r][col] = acc[r];
            }
            __syncthreads();

            // ---- stage 8: memory update ----
            {
                int j = tid & 255;
                for (int r = tid >> 8; r < 4; r += 2) {
                    float g1raw = sPart[0][r][j] + sPart[1][r][j] + wsf[1024 + j];
                    float g2raw = sPart[0][r][256 + j] + sPart[1][r][256 + j] + wsf[1280 + j];
                    float g1v = sigm(g1raw);
                    float g2v = sigm(g2raw);
                    float ch = tanh_fast(sCp[0][r][j] + sCp[1][r][j] + a2b2[j]);
                    float m2 = g1v * sM[r][j] + g2v * ch;
                    sM[r][j] = m2;
                    float m2o = __shfl_xor(m2, 1);
                    if (!(j & 1)) pM[r][j >> 1] = pk2(m2, m2o);
                }
            }
            __syncthreads();
        }

        // ---- B epilogue ----
        {
            float acc[4] = {0.f, 0.f, 0.f, 0.f};
            gpart<1, 3>(acc, &pM[0][0], 128, 128, wsu + OFF_OW1 + 192L * 512 + 2 * tid, 512);
            if (tid == 0) {
                while (__hip_atomic_load(flagA + g, __ATOMIC_ACQUIRE,
                                         __HIP_MEMORY_SCOPE_AGENT) < 1000)
                    __builtin_amdgcn_s_sleep(2);
            }
            __syncthreads();
            float wv2 = ow2[tid], b = ob1[tid];
            float pr[4];
#pragma unroll
            for (int r = 0; r < 4; ++r) {
                float ap = __uint_as_float(ATOMIC_LD_AG(owp + (long)(row0 + r) * 512 + tid));
                float h = fmaxf(acc[r] + ap + b, 0.f);
                pr[r] = h * wv2;
            }
#pragma unroll
            for (int o = 32; o; o >>= 1) {
#pragma unroll
                for (int r = 0; r < 4; ++r) pr[r] += __shfl_xor(pr[r], o);
            }
            int wvid = tid >> 6, ln = tid & 63;
            if (ln == 0) {
#pragma unroll
                for (int r = 0; r < 4; ++r) sRed2[wvid][r] = pr[r];
            }
            __syncthreads();
            if (tid < 4) {
                float s = 0.f;
#pragma unroll
                for (int w = 0; w < 8; ++w) s += sRed2[w][tid];
                out[row0 + tid] = s + ob2[0];
            }
        }
    }
}

extern "C" void kernel_launch(void* const* d_in, const int* in_sizes, int n_in,
                              void* d_out, int out_size, void* d_ws, size_t ws_size,
                              hipStream_t stream)
{
    const float* x_p  = (const float*)d_in[0];
    const float* c_t  = (const float*)d_in[1];
    const float* c_a  = (const float*)d_in[2];
    const float* c_v  = (const float*)d_in[3];
    const float* memp = (const float*)d_in[4];

    u32* wsu = (u32*)d_ws;
    float* wsf = (float*)((char*)d_ws + (size_t)U32_TOTAL * 4);

    // zero AWI pad region + sync flags (both re-run every graph replay)
    hipMemsetAsync((char*)d_ws + (size_t)OFF_AWI * 4, 0, (size_t)(OFF_VWI - OFF_AWI) * 4, stream);
    hipMemsetAsync((char*)d_ws + (size_t)FLAGS_OFF * 4, 0, 1024, stream);

    auto T = [&](const void* src, long off, int N, int K, int strideU, int rowOffK, int colOff) {
        long total = (long)N * K;
        int blocks = (int)((total + 255) / 256);
        hipLaunchKernelGGL(k_transpose, dim3(blocks), dim3(256), 0, stream,
                           (const float*)src, (unsigned short*)(wsu + off), N, K, strideU, rowOffK, colOff);
    };
    T(d_in[5],  OFF_TWI,  1024, 300, 1024, 0,   0);   // t_Wi
    T(d_in[6],  OFF_TWI,  1024, 256, 1024, 300, 0);   // t_Wh
    T(d_in[8],  OFF_AWI,  256,  74,  256,  0,   0);   // a_Wi (74,75 zero pad)
    T(d_in[9],  OFF_AWI,  256,  64,  256,  76,  0);   // a_Wh
    T(d_in[11], OFF_VWI,  256,  36,  256,  0,   0);   // v_Wi
    T(d_in[12], OFF_VWI,  256,  64,  256,  36,  0);   // v_Wh
    T(d_in[14], OFF_A1W1, 512,  768, 512,  0,   0);   // attn1_w1
    T(d_in[16], OFF_A1W2, 768,  512, 768,  0,   0);   // attn1_w2
    T(d_in[18], OFF_A2W1, 512,  768, 512,  0,   0);   // attn2_w1
    T(d_in[20], OFF_A2W2, 256,  512, 256,  0,   0);   // attn2_w2
    T(d_in[22], OFF_GW1,  512, 1024, 1024, 0,   0);   // g1_w1
    T(d_in[26], OFF_GW1,  512, 1024, 1024, 0,   512); // g2_w1
    T(d_in[24], OFF_GW2,  256,  512, 512,  0,   0);   // g1_w2
    T(d_in[28], OFF_GW2,  256,  512, 512,  0,   256); // g2_w2
    T(d_in[30], OFF_OW1,  512,  640, 512,  0,   0);   // out_w1

    hipLaunchKernelGGL(k_packbias, dim3(6), dim3(256), 0, stream,
                       (const float*)d_in[23], (const float*)d_in[27],
                       (const float*)d_in[25], (const float*)d_in[29], wsf);

    hipLaunchKernelGGL(fused_rnn, dim3(256), dim3(512), 0, stream,
                       x_p, c_t, c_a, c_v, memp,
                       (const float*)d_in[7],  (const float*)d_in[10], (const float*)d_in[13],
                       (const float*)d_in[15], (const float*)d_in[17],
                       (const float*)d_in[19], (const float*)d_in[21],
                       (const float*)d_in[31], (const float*)d_in[32], (const float*)d_in[33],
                       wsu, wsf, wsu, (float*)d_out);
}

// Round 18
// 8820.996 us; speedup vs baseline: 3.2497x; 2.6612x over previous
//
#include <hip/hip_runtime.h>
#include <hip/hip_bf16.h>
#include <hip/hip_fp16.h>

typedef unsigned int u32;
typedef unsigned long long u64;
typedef __fp16 h2t __attribute__((ext_vector_type(2)));

// ---------------- dims ----------------
#define T_STEPS_D 128
#define NBATCH 512

// ws layout (u32 element offsets). Weights f16, QUAD-packed:
// quad q (= k-pairs 2q,2q+1), column n: u32[q*2N + 2n + s], s = pair slot (0/1).
#define OFF_TWI   0L         // pairs 278 (150 t_Wi + 128 t_Wh), N=1024
#define OFF_AWI   284672L    // pairs 70 (38 a_Wi [2 zero-pad rows] + 32 a_Wh), N=256
#define OFF_VWI   302592L    // pairs 50 (18 v_Wi + 32 v_Wh), N=256
#define OFF_A1W1  315392L    // pairs 384, N=512
#define OFF_A1W2  512000L    // pairs 256, N=768
#define OFF_A2W1  708608L    // pairs 384, N=512
#define OFF_A2W2  905216L    // pairs 256, N=256
#define OFF_GW1   970752L    // pairs 512, N=1024
#define OFF_GW2   1495040L   // pairs 256, N=512
#define OFF_OW1   1626112L   // pairs 320, N=512
#define U32_TOTAL 1789952L   // fp32 packed biases follow (1536 floats)
// pipeline comm regions (u32 offsets)
#define FLAGS_OFF 1791744L   // flagA[128], flagB[128] (memset each launch)
#define ATTQ_OFF  1792000L   // u32: 4 bufs x 512 rows x 384 pairs (8B aligned)
#define OWP_OFF   2578432L   // f32 bits: 512 rows x 512
#define ATOMIC_RLX_AG(p, v) __hip_atomic_store((p), (v), __ATOMIC_RELAXED, __HIP_MEMORY_SCOPE_AGENT)
#define ATOMIC_LD_AG(p)     __hip_atomic_load((p), __ATOMIC_RELAXED, __HIP_MEMORY_SCOPE_AGENT)

__device__ __forceinline__ float sigm(float x) { return 1.f / (1.f + __expf(-x)); }
__device__ __forceinline__ float tanh_fast(float x) {
    float e = __expf(2.f * x);
    return 1.f - 2.f / (e + 1.f);
}
__device__ __forceinline__ float dot2(u32 a, u32 b, float c) {
    union { u32 u; h2t h; } x, y; x.u = a; y.u = b;
#if __has_builtin(__builtin_amdgcn_fdot2)
    return __builtin_amdgcn_fdot2(x.h, y.h, c, false);
#else
    c += (float)x.h[0] * (float)y.h[0];
    c += (float)x.h[1] * (float)y.h[1];
    return c;
#endif
}
__device__ __forceinline__ u32 pk2(float a, float b) {
    union { h2t h; u32 u; } z;
    z.h = __builtin_amdgcn_cvt_pkrtz(a, b);
    return z.u;
}

// ---- weight block loads: one block = 8 k-pairs = 4 quads ----
__device__ __forceinline__ void gp_load1(u32* buf, const u32* __restrict__ wp, int N) {
#pragma unroll
    for (int q = 0; q < 4; ++q) {
        uint2 v = *(const uint2*)(wp + q * 2 * N);
        buf[2 * q] = v.x; buf[2 * q + 1] = v.y;
    }
}
__device__ __forceinline__ void gp_load2(u32* buf, const u32* __restrict__ wp, int N) {
#pragma unroll
    for (int q = 0; q < 4; ++q) {
        uint4 v = *(const uint4*)(wp + q * 2 * N);
        buf[4 * q] = v.x; buf[4 * q + 1] = v.y; buf[4 * q + 2] = v.z; buf[4 * q + 3] = v.w;
    }
}

// compute one block: 8 k-pairs x 4 rows x NC cols. acc[NC*r+c].
template<int NC>
__device__ __forceinline__ void gp_comp(float* acc, const u32* __restrict__ a, int stA,
                                        int kb, const u32* buf) {
#pragma unroll
    for (int r = 0; r < 4; ++r) {
        uint4 xa = *(const uint4*)(a + r * stA + kb);
        uint4 xb = *(const uint4*)(a + r * stA + kb + 4);
        u32 av[8] = {xa.x, xa.y, xa.z, xa.w, xb.x, xb.y, xb.z, xb.w};
#pragma unroll
        for (int p = 0; p < 8; ++p) {
            if constexpr (NC == 1) {
                acc[r] = dot2(buf[p], av[p], acc[r]);
            } else {
                acc[2 * r]     = dot2(buf[4 * (p >> 1) + (p & 1)],     av[p], acc[2 * r]);
                acc[2 * r + 1] = dot2(buf[4 * (p >> 1) + 2 + (p & 1)], av[p], acc[2 * r + 1]);
            }
        }
    }
}

// acc[NC*r+c] += sum_k a[r][k] * W[k][col_base+c]. Register prefetch pipeline.
// NC=2 MUST stay DEPTH<=2 under the 128-VGPR cap (R16/R17: deeper spilled).
template<int NC, int DEPTH>
__device__ __forceinline__ void gpart(float* acc, const u32* __restrict__ a, int k2, int stA,
                                      const u32* __restrict__ w, int N)
{
    const int nb = k2 >> 3;
    u32 b0[NC * 8], b1[NC * 8], b2[NC * 8];
#define GLOAD(B, P) do { if constexpr (NC == 1) gp_load1(B, w + (long)(P) * 8 * N, N); \
                         else gp_load2(B, w + (long)(P) * 8 * N, N); } while (0)
    if (nb > 0) GLOAD(b0, 0);
    if (DEPTH > 1 && nb > 1) GLOAD(b1, 1);
    if (DEPTH > 2 && nb > 2) GLOAD(b2, 2);
    int i = 0;
    while (i < nb) {
        gp_comp<NC>(acc, a, stA, i * 8, b0);
        if (i + DEPTH < nb) GLOAD(b0, i + DEPTH);
        ++i; if (i >= nb) break;
        gp_comp<NC>(acc, a, stA, i * 8, b1);
        if (i + DEPTH < nb) GLOAD(b1, i + DEPTH);
        ++i; if (i >= nb) break;
        if (DEPTH > 2) {
            gp_comp<NC>(acc, a, stA, i * 8, b2);
            if (i + DEPTH < nb) GLOAD(b2, i + DEPTH);
            ++i;
        }
    }
#undef GLOAD
    for (int p = nb * 8; p < k2; ++p) {     // tail (<8 pairs)
        const u32* wp = w + (long)(p >> 1) * 2 * N + (p & 1);
#pragma unroll
        for (int r = 0; r < 4; ++r) {
            u32 aa = a[r * stA + p];
            if constexpr (NC == 1) {
                acc[r] = dot2(wp[0], aa, acc[r]);
            } else {
                acc[2 * r]     = dot2(wp[0], aa, acc[2 * r]);
                acc[2 * r + 1] = dot2(wp[2], aa, acc[2 * r + 1]);
            }
        }
    }
}

// -------- prologue kernels --------
__global__ void k_transpose(const float* __restrict__ src, unsigned short* __restrict__ dst,
                            int N, int K, int strideU, int rowOffK, int colOff)
{
    long i = (long)blockIdx.x * 256 + threadIdx.x;
    if (i >= (long)N * K) return;
    int n = (int)(i / K);
    int k = (int)(i - (long)n * K);
    __half h = __float2half(src[i]);
    long kk = k + rowOffK;
    long idx32 = (kk >> 2) * 2L * strideU + 2L * (colOff + n) + ((kk >> 1) & 1);
    dst[idx32 * 2 + (kk & 1)] = __half_as_ushort(h);
}

__global__ void k_packbias(const float* __restrict__ g1b1, const float* __restrict__ g2b1,
                           const float* __restrict__ g1b2, const float* __restrict__ g2b2,
                           float* __restrict__ gb)
{
    int i = blockIdx.x * 256 + threadIdx.x;
    if (i < 512) gb[i] = g1b1[i];
    else if (i < 1024) gb[i] = g2b1[i - 512];
    else if (i < 1280) gb[i] = g1b2[i - 1024];
    else if (i < 1536) gb[i] = g2b2[i - 1280];
}

// -------- main: 256 WGs x 512 threads; role split by XCD (bid%8) --------
// A (XCD 0-3): LSTMs + attn1 + softmax + attended  -> stream 2.85MB/step
// B (XCD 4-7): attn2 + gates + memory              -> stream 3.67MB/step
// Cross-XCD payloads (attq, owp) use AGENT-scope atomics (device coherence point)
// -- regular stores raced on graph replay (R14). Bare launch_bounds(512) is the
// ONLY config that holds VGPR=128 without spilling (R6/7/8/12/16/17 lessons).
__global__ __launch_bounds__(512)
void fused_rnn(const float* __restrict__ x_p,
               const float* __restrict__ c_t0, const float* __restrict__ c_a0,
               const float* __restrict__ c_v0, const float* __restrict__ mem0,
               const float* __restrict__ t_b, const float* __restrict__ a_b,
               const float* __restrict__ v_b,
               const float* __restrict__ a1b1, const float* __restrict__ a1b2,
               const float* __restrict__ a2b1, const float* __restrict__ a2b2,
               const float* __restrict__ ob1, const float* __restrict__ ow2,
               const float* __restrict__ ob2,
               const u32* __restrict__ wsu, const float* __restrict__ wsf,
               u32* wsrw,
               float* __restrict__ out)
{
    const int tid = threadIdx.x;
    const int xcd = (int)blockIdx.x & 7;
    const bool isA = xcd < 4;
    const int g = ((int)blockIdx.x >> 3) * 4 + (xcd & 3);
    const int row0 = g * 4;

    int* flagA = (int*)(wsrw + FLAGS_OFF);
    int* flagB = flagA + 128;
    u32* attq = wsrw + ATTQ_OFF;
    u32* owp = wsrw + OWP_OFF;

    // fp32 buffers
    __shared__ alignas(16) float sZ[4][1024];
    __shared__ alignas(16) float sZa[4][256];
    __shared__ alignas(16) float sZv[4][256];
    __shared__ alignas(16) float sTc[4][256];
    __shared__ alignas(16) float sAc[4][64];
    __shared__ alignas(16) float sVc[4][64];
    __shared__ alignas(16) float sM[4][256];
    __shared__ alignas(16) float sCs[4][768];
    __shared__ alignas(16) float sCp[2][4][256];
    __shared__ alignas(16) float sHid[4][512];
    __shared__ alignas(16) float sPart[2][4][512];
    // packed f16-pair buffers
    __shared__ alignas(16) u32 pX[4][212];
    __shared__ alignas(16) u32 pCs[4][384];
    __shared__ alignas(16) u32 pTh[4][128];
    __shared__ alignas(16) u32 pAh[4][32];
    __shared__ alignas(16) u32 pVh[4][32];
    __shared__ alignas(16) u32 pM[4][128];
    __shared__ alignas(16) u32 pHid[4][256];
    __shared__ alignas(16) u32 pZ[4][512];
    __shared__ float sRed[4];
    __shared__ float sRed2[8][4];

    if (isA) {
        // ================= ROLE A =================
        for (int i = tid; i < 4 * 128; i += 512) {
            int r = i >> 7, j2 = i & 127, j = 2 * j2;
            sTc[r][j] = c_t0[(row0 + r) * 256 + j];
            sTc[r][j + 1] = c_t0[(row0 + r) * 256 + j + 1];
            pTh[r][j2] = 0u;
        }
        for (int i = tid; i < 4 * 32; i += 512) {
            int r = i >> 5, j2 = i & 31, j = 2 * j2;
            sAc[r][j] = c_a0[(row0 + r) * 64 + j]; sAc[r][j + 1] = c_a0[(row0 + r) * 64 + j + 1];
            sVc[r][j] = c_v0[(row0 + r) * 64 + j]; sVc[r][j + 1] = c_v0[(row0 + r) * 64 + j + 1];
            pAh[r][j2] = 0u; pVh[r][j2] = 0u;
        }
        if (tid < 12) pX[tid / 3][189 + tid % 3] = 0u;
        __syncthreads();

        for (int t = 0; t < T_STEPS_D; ++t) {
            if (t >= 4) {   // quad-buffer reuse guard
                if (tid == 0) {
                    while (__hip_atomic_load(flagB + g, __ATOMIC_ACQUIRE,
                                             __HIP_MEMORY_SCOPE_AGENT) < t - 3)
                        __builtin_amdgcn_s_sleep(2);
                }
                __syncthreads();
            }
            // ---- stage 1 ----
            const float* xb = x_p + ((long)t * NBATCH + row0) * 410;
            for (int i = tid; i < 4 * 205; i += 512) {
                int r = i / 205, p = i - r * 205;
                float2 v = *(const float2*)(xb + r * 410 + 2 * p);
                int dst = (p < 150) ? p : (p < 187 ? p + 2 : p + 5);
                pX[r][dst] = pk2(v.x, v.y);
            }
            for (int i = tid; i < 4 * 192; i += 512) {
                int r = i / 192, p = i - r * 192;
                float v0, v1; int c;
                if (p < 128) { c = 2 * p; v0 = sTc[r][c]; v1 = sTc[r][c + 1]; }
                else if (p < 160) { int j = 2 * (p - 128); c = 256 + j; v0 = sAc[r][j]; v1 = sAc[r][j + 1]; }
                else { int j = 2 * (p - 160); c = 320 + j; v0 = sVc[r][j]; v1 = sVc[r][j + 1]; }
                sCs[r][c] = v0; sCs[r][c + 1] = v1;
                pCs[r][p] = pk2(v0, v1);
            }
            __syncthreads();

            // ---- stage 2 ----
            {
                float acc[8] = {0.f, 0.f, 0.f, 0.f, 0.f, 0.f, 0.f, 0.f};
                gpart<2, 2>(acc, &pX[0][0], 150, 212, wsu + OFF_TWI + 4 * tid, 1024);
                gpart<2, 2>(acc, &pTh[0][0], 128, 128, wsu + OFF_TWI + 150L * 1024 + 4 * tid, 1024);
                float bb0 = t_b[2 * tid], bb1 = t_b[2 * tid + 1];
#pragma unroll
                for (int r = 0; r < 4; ++r) {
                    sZ[r][2 * tid] = acc[2 * r] + bb0;
                    sZ[r][2 * tid + 1] = acc[2 * r + 1] + bb1;
                }
            }
            if (tid < 256) {
                float acc[4] = {0.f, 0.f, 0.f, 0.f};
                gpart<1, 3>(acc, &pX[0][152], 38, 212, wsu + OFF_AWI + 2 * tid, 256);
                gpart<1, 3>(acc, &pAh[0][0], 32, 32, wsu + OFF_AWI + 38L * 256 + 2 * tid, 256);
                float b = a_b[tid];
#pragma unroll
                for (int r = 0; r < 4; ++r) sZa[r][tid] = acc[r] + b;
            } else {
                int st = tid - 256;
                float acc[4] = {0.f, 0.f, 0.f, 0.f};
                gpart<1, 3>(acc, &pX[0][192], 18, 212, wsu + OFF_VWI + 2 * st, 256);
                gpart<1, 3>(acc, &pVh[0][0], 32, 32, wsu + OFF_VWI + 18L * 256 + 2 * st, 256);
                float b = v_b[st];
#pragma unroll
                for (int r = 0; r < 4; ++r) sZv[r][st] = acc[r] + b;
            }
            __syncthreads();

            // ---- stage 3 ----
            {
                int j = tid & 255;
                for (int r = tid >> 8; r < 4; r += 2) {
                    float iv = sZ[r][j], fv = sZ[r][256 + j], gv = sZ[r][512 + j], ov = sZ[r][768 + j];
                    float c2 = sigm(fv) * sTc[r][j] + sigm(iv) * tanh_fast(gv);
                    float h2 = sigm(ov) * tanh_fast(c2);
                    sTc[r][j] = c2; sCs[r][384 + j] = c2;
                    float c2o = __shfl_xor(c2, 1), h2o = __shfl_xor(h2, 1);
                    if (!(j & 1)) {
                        pTh[r][j >> 1] = pk2(h2, h2o);
                        pCs[r][192 + (j >> 1)] = pk2(c2, c2o);
                    }
                }
                int cell = tid >> 8, r2 = (tid >> 6) & 3, j2 = tid & 63;
                if (cell == 0) {
                    float iv = sZa[r2][j2], fv = sZa[r2][64 + j2], gv = sZa[r2][128 + j2], ov = sZa[r2][192 + j2];
                    float c2 = sigm(fv) * sAc[r2][j2] + sigm(iv) * tanh_fast(gv);
                    float h2 = sigm(ov) * tanh_fast(c2);
                    sAc[r2][j2] = c2; sCs[r2][640 + j2] = c2;
                    float c2o = __shfl_xor(c2, 1), h2o = __shfl_xor(h2, 1);
                    if (!(j2 & 1)) {
                        pAh[r2][j2 >> 1] = pk2(h2, h2o);
                        pCs[r2][320 + (j2 >> 1)] = pk2(c2, c2o);
                    }
                } else {
                    float iv = sZv[r2][j2], fv = sZv[r2][64 + j2], gv = sZv[r2][128 + j2], ov = sZv[r2][192 + j2];
                    float c2 = sigm(fv) * sVc[r2][j2] + sigm(iv) * tanh_fast(gv);
                    float h2 = sigm(ov) * tanh_fast(c2);
                    sVc[r2][j2] = c2; sCs[r2][704 + j2] = c2;
                    float c2o = __shfl_xor(c2, 1), h2o = __shfl_xor(h2, 1);
                    if (!(j2 & 1)) {
                        pVh[r2][j2 >> 1] = pk2(h2, h2o);
                        pCs[r2][352 + (j2 >> 1)] = pk2(c2, c2o);
                    }
                }
            }
            __syncthreads();

            // ---- stage 4a: attn1-l1 split-K x2 ----
            {
                int half = tid >> 8, st = tid & 255;
                float acc[8] = {0.f, 0.f, 0.f, 0.f, 0.f, 0.f, 0.f, 0.f};
                gpart<2, 2>(acc, &pCs[0][half * 192], 192, 384,
                            wsu + OFF_A1W1 + (long)half * 192 * 512 + 4 * st, 512);
#pragma unroll
                for (int r = 0; r < 4; ++r) {
                    sPart[half][r][2 * st] = acc[2 * r];
                    sPart[half][r][2 * st + 1] = acc[2 * r + 1];
                }
            }
            __syncthreads();
            for (int i = tid; i < 1024; i += 512) {
                int r = i >> 8, cp = i & 255, c = 2 * cp;
                float v0 = fmaxf(sPart[0][r][c] + sPart[1][r][c] + a1b1[c], 0.f);
                float v1 = fmaxf(sPart[0][r][c + 1] + sPart[1][r][c + 1] + a1b1[c + 1], 0.f);
                pHid[r][cp] = pk2(v0, v1);
            }
            __syncthreads();

            // ---- stage 4b: attn1-l2 ----
            if (tid < 384) {
                float acc[8] = {0.f, 0.f, 0.f, 0.f, 0.f, 0.f, 0.f, 0.f};
                gpart<2, 2>(acc, &pHid[0][0], 256, 256, wsu + OFF_A1W2 + 4 * tid, 768);
                float bb0 = a1b2[2 * tid], bb1 = a1b2[2 * tid + 1];
#pragma unroll
                for (int r = 0; r < 4; ++r) {
                    sZ[r][2 * tid] = acc[2 * r] + bb0;
                    sZ[r][2 * tid + 1] = acc[2 * r + 1] + bb1;
                }
            }
            __syncthreads();

            // ---- stage 5: softmax + attended -> AGENT-scope atomic handoff ----
            {
                int wv = tid >> 6, ln = tid & 63;
                if (wv < 4) {
                    float mx = -3.0e38f;
                    for (int i = ln; i < 768; i += 64) mx = fmaxf(mx, sZ[wv][i]);
                    for (int o = 32; o; o >>= 1) mx = fmaxf(mx, __shfl_xor(mx, o));
                    float sum = 0.f;
                    for (int i = ln; i < 768; i += 64) { float e = __expf(sZ[wv][i] - mx); sZ[wv][i] = e; sum += e; }
                    for (int o = 32; o; o >>= 1) sum += __shfl_xor(sum, o);
                    if (ln == 0) sRed[wv] = 1.f / sum;
                }
            }
            __syncthreads();
            {
                u64* dst = (u64*)(attq + ((long)(t & 3) * NBATCH + row0) * 384);
                for (int ii = tid; ii < 768; ii += 512) {
                    int base = 2 * ii;
                    int r = base / 384, p = base - r * 384, c = 2 * p;
                    float s = sRed[r];
                    u32 w0 = pk2(sZ[r][c] * s * sCs[r][c], sZ[r][c + 1] * s * sCs[r][c + 1]);
                    u32 w1 = pk2(sZ[r][c + 2] * s * sCs[r][c + 2], sZ[r][c + 3] * s * sCs[r][c + 3]);
                    ATOMIC_RLX_AG(dst + ii, (u64)w0 | ((u64)w1 << 32));
                }
            }
            __syncthreads();
            if (tid == 0)
                __hip_atomic_store(flagA + g, t + 1, __ATOMIC_RELEASE, __HIP_MEMORY_SCOPE_AGENT);
        }

        // ---- A epilogue: partial output head (th/ah/vh) -> owp via atomics ----
        {
            float acc[4] = {0.f, 0.f, 0.f, 0.f};
            gpart<1, 3>(acc, &pTh[0][0], 128, 128, wsu + OFF_OW1 + 2 * tid, 512);
            gpart<1, 3>(acc, &pAh[0][0], 32, 32, wsu + OFF_OW1 + 128L * 512 + 2 * tid, 512);
            gpart<1, 3>(acc, &pVh[0][0], 32, 32, wsu + OFF_OW1 + 160L * 512 + 2 * tid, 512);
#pragma unroll
            for (int r = 0; r < 4; ++r)
                ATOMIC_RLX_AG(owp + (long)(row0 + r) * 512 + tid, __float_as_uint(acc[r]));
        }
        __syncthreads();
        if (tid == 0)
            __hip_atomic_store(flagA + g, 1000, __ATOMIC_RELEASE, __HIP_MEMORY_SCOPE_AGENT);

    } else {
        // ================= ROLE B =================
        for (int i = tid; i < 4 * 128; i += 512) {
            int r = i >> 7, j2 = i & 127, j = 2 * j2;
            float m0 = mem0[(row0 + r) * 256 + j], m1 = mem0[(row0 + r) * 256 + j + 1];
            sM[r][j] = m0; sM[r][j + 1] = m1;
            pM[r][j2] = pk2(m0, m1);
        }
        __syncthreads();

        for (int t = 0; t < T_STEPS_D; ++t) {
            if (tid == 0) {
                while (__hip_atomic_load(flagA + g, __ATOMIC_ACQUIRE,
                                         __HIP_MEMORY_SCOPE_AGENT) < t + 1)
                    __builtin_amdgcn_s_sleep(2);
            }
            __syncthreads();
            {   // copy attended -> LDS (agent-scope atomic loads, coherent)
                const u64* src = (const u64*)(attq + ((long)(t & 3) * NBATCH + row0) * 384);
                for (int ii = tid; ii < 768; ii += 512) {
                    u64 v = ATOMIC_LD_AG(src + ii);
                    int base = 2 * ii, r = base / 384, p = base - r * 384;
                    pCs[r][p] = (u32)v;
                    pCs[r][p + 1] = (u32)(v >> 32);
                }
            }
            __syncthreads();
            if (tid == 0)
                __hip_atomic_store(flagB + g, t + 1, __ATOMIC_RELEASE, __HIP_MEMORY_SCOPE_AGENT);

            // ---- stage 6 ----
            {
                int half = tid >> 8, st = tid & 255;
                float acc[8] = {0.f, 0.f, 0.f, 0.f, 0.f, 0.f, 0.f, 0.f};
                gpart<2, 2>(acc, &pCs[0][half * 192], 192, 384,
                            wsu + OFF_A2W1 + (long)half * 192 * 512 + 4 * st, 512);
#pragma unroll
                for (int r = 0; r < 4; ++r) {
                    sPart[half][r][2 * st] = acc[2 * r];
                    sPart[half][r][2 * st + 1] = acc[2 * r + 1];
                }
            }
            {
                float acc[8] = {0.f, 0.f, 0.f, 0.f, 0.f, 0.f, 0.f, 0.f};
                gpart<2, 2>(acc, &pCs[0][0], 384, 384, wsu + OFF_GW1 + 4 * tid, 1024);
                gpart<2, 2>(acc, &pM[0][0], 128, 128, wsu + OFF_GW1 + 384L * 1024 + 4 * tid, 1024);
                float bb0 = wsf[2 * tid], bb1 = wsf[2 * tid + 1];
#pragma unroll
                for (int r = 0; r < 4; ++r) {
                    float v0 = fmaxf(acc[2 * r] + bb0, 0.f);
                    float v1 = fmaxf(acc[2 * r + 1] + bb1, 0.f);
                    pZ[r][tid] = pk2(v0, v1);
                }
            }
            __syncthreads();
            for (int i = tid; i < 1024; i += 512) {
                int r = i >> 8, cp = i & 255, c = 2 * cp;
                float v0 = fmaxf(sPart[0][r][c] + sPart[1][r][c] + a2b1[c], 0.f);
                float v1 = fmaxf(sPart[0][r][c + 1] + sPart[1][r][c + 1] + a2b1[c + 1], 0.f);
                pHid[r][cp] = pk2(v0, v1);
            }
            __syncthreads();

            // ---- stage 7 ----
            {
                int half = tid >> 8, st = tid & 255;
                float acc[8] = {0.f, 0.f, 0.f, 0.f, 0.f, 0.f, 0.f, 0.f};
                const u32* actb = &pZ[0][(st >= 128 ? 256 : 0) + half * 128];
                gpart<2, 2>(acc, actb, 128, 512,
                            wsu + OFF_GW2 + (long)half * 128 * 512 + 4 * st, 512);
#pragma unroll
                for (int r = 0; r < 4; ++r) {
                    sPart[half][r][2 * st] = acc[2 * r];
                    sPart[half][r][2 * st + 1] = acc[2 * r + 1];
                }
            }
            {
                int kh = tid >> 8, col = tid & 255;
                float acc[4] = {0.f, 0.f, 0.f, 0.f};
                gpart<1, 3>(acc, &pHid[0][kh * 128], 128, 256,
                            wsu + OFF_A2W2 + (long)kh * 128 * 256 + 2 * col, 256);
#pragma unroll
                for (int r = 0; r < 4; ++r) sCp[kh][r][col] = acc[r];
            }
            __syncthreads();

            // ---- stage 8 ----
            {
                int j = tid & 255;
                for (int r = tid >> 8; r < 4; r += 2) {
                    float g1raw = sPart[0][r][j] + sPart[1][r][j] + wsf[1024 + j];
                    float g2raw = sPart[0][r][256 + j] + sPart[1][r][256 + j] + wsf[1280 + j];
                    float g1v = sigm(g1raw);
                    float g2v = sigm(g2raw);
                    float ch = tanh_fast(sCp[0][r][j] + sCp[1][r][j] + a2b2[j]);
                    float m2 = g1v * sM[r][j] + g2v * ch;
                    sM[r][j] = m2;
                    float m2o = __shfl_xor(m2, 1);
                    if (!(j & 1)) pM[r][j >> 1] = pk2(m2, m2o);
                }
            }
            __syncthreads();
        }

        // ---- B epilogue ----
        {
            float acc[4] = {0.f, 0.f, 0.f, 0.f};
            gpart<1, 3>(acc, &pM[0][0], 128, 128, wsu + OFF_OW1 + 192L * 512 + 2 * tid, 512);
            if (tid == 0) {
                while (__hip_atomic_load(flagA + g, __ATOMIC_ACQUIRE,
                                         __HIP_MEMORY_SCOPE_AGENT) < 1000)
                    __builtin_amdgcn_s_sleep(2);
            }
            __syncthreads();
            float wv2 = ow2[tid], b = ob1[tid];
            float pr[4];
#pragma unroll
            for (int r = 0; r < 4; ++r) {
                float ap = __uint_as_float(ATOMIC_LD_AG(owp + (long)(row0 + r) * 512 + tid));
                float h = fmaxf(acc[r] + ap + b, 0.f);
                pr[r] = h * wv2;
            }
#pragma unroll
            for (int o = 32; o; o >>= 1) {
#pragma unroll
                for (int r = 0; r < 4; ++r) pr[r] += __shfl_xor(pr[r], o);
            }
            int wvid = tid >> 6, ln = tid & 63;
            if (ln == 0) {
#pragma unroll
                for (int r = 0; r < 4; ++r) sRed2[wvid][r] = pr[r];
            }
            __syncthreads();
            if (tid < 4) {
                float s = 0.f;
#pragma unroll
                for (int w = 0; w < 8; ++w) s += sRed2[w][tid];
                out[row0 + tid] = s + ob2[0];
            }
        }
    }
}

extern "C" void kernel_launch(void* const* d_in, const int* in_sizes, int n_in,
                              void* d_out, int out_size, void* d_ws, size_t ws_size,
                              hipStream_t stream)
{
    const float* x_p  = (const float*)d_in[0];
    const float* c_t  = (const float*)d_in[1];
    const float* c_a  = (const float*)d_in[2];
    const float* c_v  = (const float*)d_in[3];
    const float* memp = (const float*)d_in[4];

    u32* wsu = (u32*)d_ws;
    float* wsf = (float*)((char*)d_ws + (size_t)U32_TOTAL * 4);

    // zero AWI pad region + sync flags (both re-run every graph replay)
    hipMemsetAsync((char*)d_ws + (size_t)OFF_AWI * 4, 0, (size_t)(OFF_VWI - OFF_AWI) * 4, stream);
    hipMemsetAsync((char*)d_ws + (size_t)FLAGS_OFF * 4, 0, 1024, stream);

    auto T = [&](const void* src, long off, int N, int K, int strideU, int rowOffK, int colOff) {
        long total = (long)N * K;
        int blocks = (int)((total + 255) / 256);
        hipLaunchKernelGGL(k_transpose, dim3(blocks), dim3(256), 0, stream,
                           (const float*)src, (unsigned short*)(wsu + off), N, K, strideU, rowOffK, colOff);
    };
    T(d_in[5],  OFF_TWI,  1024, 300, 1024, 0,   0);   // t_Wi
    T(d_in[6],  OFF_TWI,  1024, 256, 1024, 300, 0);   // t_Wh
    T(d_in[8],  OFF_AWI,  256,  74,  256,  0,   0);   // a_Wi (74,75 zero pad)
    T(d_in[9],  OFF_AWI,  256,  64,  256,  76,  0);   // a_Wh
    T(d_in[11], OFF_VWI,  256,  36,  256,  0,   0);   // v_Wi
    T(d_in[12], OFF_VWI,  256,  64,  256,  36,  0);   // v_Wh
    T(d_in[14], OFF_A1W1, 512,  768, 512,  0,   0);   // attn1_w1
    T(d_in[16], OFF_A1W2, 768,  512, 768,  0,   0);   // attn1_w2
    T(d_in[18], OFF_A2W1, 512,  768, 512,  0,   0);   // attn2_w1
    T(d_in[20], OFF_A2W2, 256,  512, 256,  0,   0);   // attn2_w2
    T(d_in[22], OFF_GW1,  512, 1024, 1024, 0,   0);   // g1_w1
    T(d_in[26], OFF_GW1,  512, 1024, 1024, 0,   512); // g2_w1
    T(d_in[24], OFF_GW2,  256,  512, 512,  0,   0);   // g1_w2
    T(d_in[28], OFF_GW2,  256,  512, 512,  0,   256); // g2_w2
    T(d_in[30], OFF_OW1,  512,  640, 512,  0,   0);   // out_w1

    hipLaunchKernelGGL(k_packbias, dim3(6), dim3(256), 0, stream,
                       (const float*)d_in[23], (const float*)d_in[27],
                       (const float*)d_in[25], (const float*)d_in[29], wsf);

    hipLaunchKernelGGL(fused_rnn, dim3(256), dim3(512), 0, stream,
                       x_p, c_t, c_a, c_v, memp,
                       (const float*)d_in[7],  (const float*)d_in[10], (const float*)d_in[13],
                       (const float*)d_in[15], (const float*)d_in[17],
                       (const float*)d_in[19], (const float*)d_in[21],
                       (const float*)d_in[31], (const float*)d_in[32], (const float*)d_in[33],
                       wsu, wsf, wsu, (float*)d_out);
}